// Round 1
// baseline (297.140 us; speedup 1.0000x reference)
//
#include <hip/hip_runtime.h>
#include <hip/hip_bf16.h>

// B=4, N=128, L=20, D=512
#define Bc 4
#define Nc 128
#define Lc 20
#define Dc 512
#define SCALE 0.04419417382415922f   // 1/sqrt(512)

// ---------------------------------------------------------------------------
// Kernel 1/2: C[M,Nout] = A[M,K] @ W[Nout,K]^T + bias[Nout]   (16x16 LDS tiles)
// ---------------------------------------------------------------------------
__global__ void gemm_bias_nt(const float* __restrict__ A,
                             const float* __restrict__ W,
                             const float* __restrict__ bias,
                             float* __restrict__ C,
                             int M, int Nout, int K) {
    __shared__ float As[16][17];
    __shared__ float Ws[16][17];
    const int tx = threadIdx.x, ty = threadIdx.y;
    const int row  = blockIdx.y * 16 + ty;
    const int col0 = blockIdx.x * 16;
    const int col  = col0 + tx;
    float acc = 0.f;
    for (int k0 = 0; k0 < K; k0 += 16) {
        As[ty][tx] = (row < M) ? A[row * K + k0 + tx] : 0.f;
        const int wrow = col0 + ty;
        Ws[ty][tx] = (wrow < Nout) ? W[wrow * K + k0 + tx] : 0.f;
        __syncthreads();
#pragma unroll
        for (int kk = 0; kk < 16; kk++) acc += As[ty][kk] * Ws[tx][kk];
        __syncthreads();
    }
    if (row < M && col < Nout) C[row * Nout + col] = acc + bias[col];
}

// ---------------------------------------------------------------------------
// Kernel 3: cross-attention over L=20 + sentence gate -> f_bq[b,n,:]
// one block per (b,n), 256 threads (4 waves)
// ---------------------------------------------------------------------------
__global__ void cross_attn_gate(const float* __restrict__ q,    // [B*N, D]
                                const float* __restrict__ k,    // [B*L, D]
                                const float* __restrict__ f_w,  // [B*L, D]
                                const float* __restrict__ f_b,  // [B*N, D]
                                const float* __restrict__ f_s,  // [B, D]
                                float* __restrict__ f_bq) {     // [B*N, D]
    const int bn = blockIdx.x;          // b*N + n
    const int b  = bn >> 7;
    const int t  = threadIdx.x;         // 0..255
    const int lane = t & 63, wave = t >> 6;

    __shared__ float qs[Dc];
    __shared__ float sc[32];
    __shared__ float red0;

    qs[t]       = q[bn * Dc + t];
    qs[t + 256] = q[bn * Dc + t + 256];
    __syncthreads();

    for (int l = wave; l < Lc; l += 4) {
        const float* kr = k + (b * Lc + l) * Dc;
        float s = 0.f;
#pragma unroll
        for (int off = 0; off < Dc; off += 64) s += qs[lane + off] * kr[lane + off];
#pragma unroll
        for (int d = 32; d >= 1; d >>= 1) s += __shfl_down(s, d, 64);
        if (lane == 0) sc[l] = s * SCALE;
    }
    __syncthreads();

    if (t == 0) {
        float mx = sc[0];
        for (int l = 1; l < Lc; l++) mx = fmaxf(mx, sc[l]);
        float sum = 0.f;
        for (int l = 0; l < Lc; l++) { float e = __expf(sc[l] - mx); sc[l] = e; sum += e; }
        red0 = 1.0f / sum;
    }
    __syncthreads();
    const float inv = red0;

#pragma unroll
    for (int half = 0; half < 2; half++) {
        const int d = t + half * 256;
        float acc = 0.f;
#pragma unroll 4
        for (int l = 0; l < Lc; l++) acc += sc[l] * f_w[(b * Lc + l) * Dc + d];
        acc = acc * inv + f_s[b * Dc + d];          // f_baq + f_s
        f_bq[bn * Dc + d] = f_b[bn * Dc + d] * acc; // gate
    }
}

// ---------------------------------------------------------------------------
// Kernel 4: A_b[b,n,:] = softmax(f_bq[b,n]·f_bq[b,m] * scale) over m
// one block per (b,n), 128 threads (thread = m)
// ---------------------------------------------------------------------------
__global__ void self_attn_scores(const float* __restrict__ f_bq,  // [B*N, D]
                                 float* __restrict__ A_b) {       // [B*N, N]
    const int bn = blockIdx.x;
    const int b  = bn >> 7;
    const int m  = threadIdx.x;   // 0..127

    __shared__ float qrow[Dc];
    __shared__ float red[Nc];

    const float* qr = f_bq + bn * Dc;
    qrow[m]       = qr[m];
    qrow[m + 128] = qr[m + 128];
    qrow[m + 256] = qr[m + 256];
    qrow[m + 384] = qr[m + 384];
    __syncthreads();

    const float4* kr = (const float4*)(f_bq + (b * Nc + m) * Dc);
    float acc = 0.f;
#pragma unroll 4
    for (int d4 = 0; d4 < Dc / 4; d4++) {
        float4 v = kr[d4];
        acc += qrow[d4 * 4 + 0] * v.x + qrow[d4 * 4 + 1] * v.y +
               qrow[d4 * 4 + 2] * v.z + qrow[d4 * 4 + 3] * v.w;
    }
    const float s = acc * SCALE;

    // block max
    red[m] = s;
    __syncthreads();
    for (int st = 64; st >= 1; st >>= 1) {
        if (m < st) red[m] = fmaxf(red[m], red[m + st]);
        __syncthreads();
    }
    const float mx = red[0];
    __syncthreads();

    const float e = __expf(s - mx);
    red[m] = e;
    __syncthreads();
    for (int st = 64; st >= 1; st >>= 1) {
        if (m < st) red[m] += red[m + st];
        __syncthreads();
    }
    A_b[bn * Nc + m] = e * (1.0f / red[0]);
}

// ---------------------------------------------------------------------------
// Kernel 5: gated moment reduction partials.
// part[c][b,j,d] = sum_{i in chunk c} A_b[b,i,j] * sigmoid(f_m*f_s)*f_m
// grid = (B*N, 4), block = 128 threads (thread = float4 lane over d)
// ---------------------------------------------------------------------------
__device__ __forceinline__ float gated(float m, float s) {
    const float x = m * s;
    const float g = __builtin_amdgcn_rcpf(1.0f + __expf(-x));
    return g * m;
}

__global__ void moment_partial(const float* __restrict__ f_m,  // [B,N,N,D]
                               const float* __restrict__ f_s,  // [B,D]
                               const float* __restrict__ A_b,  // [B*N, N]
                               float* __restrict__ part) {     // [4][B*N, D]
    const int bj    = blockIdx.x;        // b*N + j
    const int b     = bj >> 7, j = bj & 127;
    const int chunk = blockIdx.y;        // 0..3
    const int i0    = chunk * 32;
    const int t     = threadIdx.x;       // 0..127 float4 lanes

    __shared__ float w[32];
    if (t < 32) w[t] = A_b[(b * Nc + i0 + t) * Nc + j];
    __syncthreads();

    const float4 s4 = ((const float4*)(f_s + b * Dc))[t];
    float4 acc = make_float4(0.f, 0.f, 0.f, 0.f);
    const float4* base = (const float4*)f_m;
    // f_m float4 index: ((b*128 + i)*128 + j)*128 + t ; i-stride = 128*128
    int idx = ((b * Nc + i0) * Nc + j) * (Dc / 4) + t;

#pragma unroll 8
    for (int i = 0; i < 32; i++) {
        const float4 m4 = base[idx];
        idx += Nc * (Dc / 4);
        const float ww = w[i];
        acc.x += ww * gated(m4.x, s4.x);
        acc.y += ww * gated(m4.y, s4.y);
        acc.z += ww * gated(m4.z, s4.z);
        acc.w += ww * gated(m4.w, s4.w);
    }
    ((float4*)part)[chunk * (Bc * Nc * Dc / 4) + bj * (Dc / 4) + t] = acc;
}

// ---------------------------------------------------------------------------
// Kernel 6: out[b,n,:] = f_b + sum_c part[c] + A_b[b,n,:] @ f_b[b,:,:]
// one block per (b,n), 128 threads (float4 lanes)
// ---------------------------------------------------------------------------
__global__ void final_reduce(const float* __restrict__ f_b,   // [B*N, D]
                             const float* __restrict__ A_b,   // [B*N, N]
                             const float* __restrict__ part,  // [4][B*N, D]
                             float* __restrict__ out) {       // [B*N, D]
    const int bn = blockIdx.x;
    const int b  = bn >> 7, n = bn & 127;
    const int t  = threadIdx.x;  // 0..127

    __shared__ float arow[Nc];
    arow[t] = A_b[bn * Nc + t];
    __syncthreads();

    const float4* fb4 = (const float4*)(f_b + b * Nc * Dc);  // [128][128] float4
    float4 v = fb4[n * (Dc / 4) + t];
    float4 acc = v;  // + f_b

#pragma unroll
    for (int c = 0; c < 4; c++) {
        const float4 p = ((const float4*)part)[c * (Bc * Nc * Dc / 4) + bn * (Dc / 4) + t];
        acc.x += p.x; acc.y += p.y; acc.z += p.z; acc.w += p.w;
    }

#pragma unroll 8
    for (int m = 0; m < Nc; m++) {
        const float a = arow[m];
        const float4 fv = fb4[m * (Dc / 4) + t];
        acc.x += a * fv.x; acc.y += a * fv.y; acc.z += a * fv.z; acc.w += a * fv.w;
    }
    ((float4*)out)[bn * (Dc / 4) + t] = acc;
}

// ---------------------------------------------------------------------------
extern "C" void kernel_launch(void* const* d_in, const int* in_sizes, int n_in,
                              void* d_out, int out_size, void* d_ws, size_t ws_size,
                              hipStream_t stream) {
    const float* f_b = (const float*)d_in[0];
    const float* f_w = (const float*)d_in[1];
    const float* f_s = (const float*)d_in[2];
    const float* f_m = (const float*)d_in[3];
    const float* Wq  = (const float*)d_in[4];
    const float* bq  = (const float*)d_in[5];
    const float* Wk  = (const float*)d_in[6];
    const float* bk  = (const float*)d_in[7];
    float* out = (float*)d_out;

    float* ws   = (float*)d_ws;
    float* q    = ws;                 // B*N*D   = 262144
    float* k    = q    + Bc*Nc*Dc;    // B*L*D   =  40960
    float* f_bq = k    + Bc*Lc*Dc;    // B*N*D   = 262144
    float* A_b  = f_bq + Bc*Nc*Dc;    // B*N*N   =  65536
    float* part = A_b  + Bc*Nc*Nc;    // 4*B*N*D = 1048576

    dim3 blk16(16, 16);
    gemm_bias_nt<<<dim3(Dc/16, (Bc*Nc)/16), blk16, 0, stream>>>(f_b, Wq, bq, q, Bc*Nc, Dc, Dc);
    gemm_bias_nt<<<dim3(Dc/16, (Bc*Lc)/16), blk16, 0, stream>>>(f_w, Wk, bk, k, Bc*Lc, Dc, Dc);
    cross_attn_gate<<<Bc*Nc, 256, 0, stream>>>(q, k, f_w, f_b, f_s, f_bq);
    self_attn_scores<<<Bc*Nc, Nc, 0, stream>>>(f_bq, A_b);
    moment_partial<<<dim3(Bc*Nc, 4), Dc/4, 0, stream>>>(f_m, f_s, A_b, part);
    final_reduce<<<Bc*Nc, Dc/4, 0, stream>>>(f_b, A_b, part, out);
}

// Round 2
// 264.313 us; speedup vs baseline: 1.1242x; 1.1242x over previous
//
#include <hip/hip_runtime.h>
#include <hip/hip_bf16.h>

// B=4, N=128, L=20, D=512
#define Bc 4
#define Nc 128
#define Lc 20
#define Dc 512
#define SCALE 0.04419417382415922f   // 1/sqrt(512)

#if __has_builtin(__builtin_amdgcn_exp2f)
#define EXP2(x) __builtin_amdgcn_exp2f(x)
#else
#define EXP2(x) __expf((x) * 0.6931471805599453f)
#endif

// ---------------------------------------------------------------------------
// Kernel 1: fused q/k projection.
//   q = f_b @ Wq^T + bq   (rows 0..511,  blockIdx.y 0..31)
//   k = f_w @ Wk^T + bk   (rows 0..79,   blockIdx.y 32..36)
// 16x16 LDS tiles; 512 and 80 are both multiples of 16 -> no bounds checks.
// ---------------------------------------------------------------------------
__global__ void fused_gemm(const float* __restrict__ f_b,
                           const float* __restrict__ f_w,
                           const float* __restrict__ Wq,
                           const float* __restrict__ bq,
                           const float* __restrict__ Wk,
                           const float* __restrict__ bk,
                           float* __restrict__ q,
                           float* __restrict__ k) {
    const bool is_q = blockIdx.y < 32;
    const float* A    = is_q ? f_b : f_w;
    const float* W    = is_q ? Wq : Wk;
    const float* bias = is_q ? bq : bk;
    float* C          = is_q ? q : k;
    const int row0 = (is_q ? blockIdx.y : (blockIdx.y - 32)) * 16;

    __shared__ float As[16][17];
    __shared__ float Ws[16][17];
    const int tx = threadIdx.x, ty = threadIdx.y;
    const int row  = row0 + ty;
    const int col0 = blockIdx.x * 16;
    const int col  = col0 + tx;
    float acc = 0.f;
    for (int k0 = 0; k0 < Dc; k0 += 16) {
        As[ty][tx] = A[row * Dc + k0 + tx];
        Ws[ty][tx] = W[(col0 + ty) * Dc + k0 + tx];
        __syncthreads();
#pragma unroll
        for (int kk = 0; kk < 16; kk++) acc += As[ty][kk] * Ws[tx][kk];
        __syncthreads();
    }
    C[row * Dc + col] = acc + bias[col];
}

// ---------------------------------------------------------------------------
// Kernel 2: cross-attention over L=20 + sentence gate -> f_bq[b,n,:]
// one block per (b,n), 256 threads (4 waves)
// ---------------------------------------------------------------------------
__global__ void cross_attn_gate(const float* __restrict__ q,    // [B*N, D]
                                const float* __restrict__ k,    // [B*L, D]
                                const float* __restrict__ f_w,  // [B*L, D]
                                const float* __restrict__ f_b,  // [B*N, D]
                                const float* __restrict__ f_s,  // [B, D]
                                float* __restrict__ f_bq) {     // [B*N, D]
    const int bn = blockIdx.x;          // b*N + n
    const int b  = bn >> 7;
    const int t  = threadIdx.x;         // 0..255
    const int lane = t & 63, wave = t >> 6;

    __shared__ float qs[Dc];
    __shared__ float sc[32];
    __shared__ float red0;

    qs[t]       = q[bn * Dc + t];
    qs[t + 256] = q[bn * Dc + t + 256];
    __syncthreads();

    for (int l = wave; l < Lc; l += 4) {
        const float* kr = k + (b * Lc + l) * Dc;
        float s = 0.f;
#pragma unroll
        for (int off = 0; off < Dc; off += 64) s += qs[lane + off] * kr[lane + off];
#pragma unroll
        for (int d = 32; d >= 1; d >>= 1) s += __shfl_down(s, d, 64);
        if (lane == 0) sc[l] = s * SCALE;
    }
    __syncthreads();

    if (t == 0) {
        float mx = sc[0];
        for (int l = 1; l < Lc; l++) mx = fmaxf(mx, sc[l]);
        float sum = 0.f;
        for (int l = 0; l < Lc; l++) { float e = __expf(sc[l] - mx); sc[l] = e; sum += e; }
        red0 = 1.0f / sum;
    }
    __syncthreads();
    const float inv = red0;

#pragma unroll
    for (int half = 0; half < 2; half++) {
        const int d = t + half * 256;
        float acc = 0.f;
#pragma unroll 4
        for (int l = 0; l < Lc; l++) acc += sc[l] * f_w[(b * Lc + l) * Dc + d];
        acc = acc * inv + f_s[b * Dc + d];          // f_baq + f_s
        f_bq[bn * Dc + d] = f_b[bn * Dc + d] * acc; // gate
    }
}

// ---------------------------------------------------------------------------
// Kernel 3: A_b[b,n,:] = softmax_m(f_bq[b,n]·f_bq[b,m] * scale)
// one block per (b,n), 256 threads; wave-per-m (coalesced), also writes A_bT.
// ---------------------------------------------------------------------------
__global__ void self_attn_scores(const float* __restrict__ f_bq,  // [B*N, D]
                                 float* __restrict__ A_b,         // [B*N, N]
                                 float* __restrict__ A_bT) {      // [B*N, N] transposed per batch
    const int bn = blockIdx.x;
    const int b  = bn >> 7, n = bn & 127;
    const int t  = threadIdx.x;          // 0..255
    const int lane = t & 63, wave = t >> 6;

    __shared__ float qrow[Dc];
    __shared__ float sc[Nc];
    __shared__ float red[Nc];

    qrow[t]       = f_bq[bn * Dc + t];
    qrow[t + 256] = f_bq[bn * Dc + 256 + t];
    __syncthreads();

    const float4* q4 = (const float4*)qrow;
    const float4 qa = q4[lane];
    const float4 qb = q4[lane + 64];

    for (int m = wave; m < Nc; m += 4) {
        const float4* kr = (const float4*)(f_bq + (b * Nc + m) * Dc);
        const float4 va = kr[lane];
        const float4 vb = kr[lane + 64];
        float s = qa.x * va.x + qa.y * va.y + qa.z * va.z + qa.w * va.w
                + qb.x * vb.x + qb.y * vb.y + qb.z * vb.z + qb.w * vb.w;
#pragma unroll
        for (int d = 32; d >= 1; d >>= 1) s += __shfl_down(s, d, 64);
        if (lane == 0) sc[m] = s * SCALE;
    }
    __syncthreads();

    float e = 0.f, sval = 0.f;
    if (t < Nc) { sval = sc[t]; red[t] = sval; }
    __syncthreads();
    for (int st = 64; st >= 1; st >>= 1) {
        if (t < st) red[t] = fmaxf(red[t], red[t + st]);
        __syncthreads();
    }
    const float mx = red[0];
    __syncthreads();
    if (t < Nc) { e = __expf(sval - mx); red[t] = e; }
    __syncthreads();
    for (int st = 64; st >= 1; st >>= 1) {
        if (t < st) red[t] += red[t + st];
        __syncthreads();
    }
    if (t < Nc) {
        const float a = e * (1.0f / red[0]);
        A_b[bn * Nc + t] = a;                 // row-major (for f_bb)
        A_bT[(b * Nc + t) * Nc + n] = a;      // transposed (for moment gather)
    }
}

// ---------------------------------------------------------------------------
// Kernel 4: fused moment reduction + self-attn apply + residual.
// out[b,j,:] = f_b[b,j,:] + sum_m A_b[b,j,m] f_b[b,m,:]
//            + sum_i A_b[b,i,j] * sigmoid(f_m*f_s)*f_m
// one block per (b,j), 256 threads: c = float4 column (0..127), half = i-split.
// ---------------------------------------------------------------------------
__global__ void moment_final(const float* __restrict__ f_m,   // [B,N,N,D]
                             const float* __restrict__ f_s,   // [B,D]
                             const float* __restrict__ A_b,   // [B*N, N]
                             const float* __restrict__ A_bT,  // [B*N, N]
                             const float* __restrict__ f_b,   // [B*N, D]
                             float* __restrict__ out) {       // [B*N, D]
    const int bj = blockIdx.x;
    const int b  = bj >> 7, j = bj & 127;
    const int t  = threadIdx.x;        // 0..255
    const int c    = t & 127;          // float4 column
    const int half = t >> 7;           // 0 or 1

    __shared__ float w[Nc];            // A_b[b,:,j]  (moment weights)
    __shared__ float ar[Nc];           // A_b[b,j,:]  (self-attn row)
    __shared__ float4 part[Nc];

    if (t < Nc) w[t] = A_bT[bj * Nc + t];
    else        ar[t - Nc] = A_b[bj * Nc + (t - Nc)];
    __syncthreads();

    const float4 s4 = ((const float4*)(f_s + b * Dc))[c];
    const float4 ns = make_float4(-1.4426950408889634f * s4.x,
                                  -1.4426950408889634f * s4.y,
                                  -1.4426950408889634f * s4.z,
                                  -1.4426950408889634f * s4.w);

    float4 acc = make_float4(0.f, 0.f, 0.f, 0.f);
    const float4* fm4 = (const float4*)f_m;
    // float4 index: ((b*128 + i)*128 + j)*128 + c ; i-stride = 128*128
    int idx = ((b * Nc + half * 64) * Nc + j) * (Dc / 4) + c;

#pragma unroll 8
    for (int i = 0; i < 64; i++) {
        const float4 m4 = fm4[idx];
        idx += Nc * (Dc / 4);
        const float ww = w[half * 64 + i];
        acc.x += ww * m4.x * __builtin_amdgcn_rcpf(1.f + EXP2(m4.x * ns.x));
        acc.y += ww * m4.y * __builtin_amdgcn_rcpf(1.f + EXP2(m4.y * ns.y));
        acc.z += ww * m4.z * __builtin_amdgcn_rcpf(1.f + EXP2(m4.z * ns.z));
        acc.w += ww * m4.w * __builtin_amdgcn_rcpf(1.f + EXP2(m4.w * ns.w));
    }

    const float4* fb4 = (const float4*)(f_b + b * Nc * Dc);
#pragma unroll 4
    for (int m = half * 64; m < half * 64 + 64; m++) {
        const float a = ar[m];
        const float4 v = fb4[m * (Dc / 4) + c];
        acc.x += a * v.x; acc.y += a * v.y; acc.z += a * v.z; acc.w += a * v.w;
    }

    if (half == 1) part[c] = acc;
    __syncthreads();
    if (half == 0) {
        const float4 p = part[c];
        const float4 r = fb4[j * (Dc / 4) + c];   // + f_b residual
        acc.x += p.x + r.x; acc.y += p.y + r.y;
        acc.z += p.z + r.z; acc.w += p.w + r.w;
        ((float4*)out)[bj * (Dc / 4) + c] = acc;
    }
}

// ---------------------------------------------------------------------------
extern "C" void kernel_launch(void* const* d_in, const int* in_sizes, int n_in,
                              void* d_out, int out_size, void* d_ws, size_t ws_size,
                              hipStream_t stream) {
    const float* f_b = (const float*)d_in[0];
    const float* f_w = (const float*)d_in[1];
    const float* f_s = (const float*)d_in[2];
    const float* f_m = (const float*)d_in[3];
    const float* Wq  = (const float*)d_in[4];
    const float* bq  = (const float*)d_in[5];
    const float* Wk  = (const float*)d_in[6];
    const float* bk  = (const float*)d_in[7];
    float* out = (float*)d_out;

    float* ws   = (float*)d_ws;
    float* q    = ws;                 // B*N*D = 262144
    float* k    = q    + Bc*Nc*Dc;    // B*L*D =  40960
    float* f_bq = k    + Bc*Lc*Dc;    // B*N*D = 262144
    float* A_b  = f_bq + Bc*Nc*Dc;    // B*N*N =  65536
    float* A_bT = A_b  + Bc*Nc*Nc;    // B*N*N =  65536

    fused_gemm<<<dim3(Dc/16, 37), dim3(16,16), 0, stream>>>(f_b, f_w, Wq, bq, Wk, bk, q, k);
    cross_attn_gate<<<Bc*Nc, 256, 0, stream>>>(q, k, f_w, f_b, f_s, f_bq);
    self_attn_scores<<<Bc*Nc, 256, 0, stream>>>(f_bq, A_b, A_bT);
    moment_final<<<Bc*Nc, 256, 0, stream>>>(f_m, f_s, A_b, A_bT, f_b, out);
}